// Round 15
// baseline (422.855 us; speedup 1.0000x reference)
//
#include <hip/hip_runtime.h>
#include <hip/hip_bf16.h>

#define HD   64
#define SEQ  2048
#define NB   256
#define TWOH 128
#define NCH  32   // SEQ / 64
#define KS   68   // padded row stride for k/v tables (16B-aligned, 8-way max)

typedef float v4f __attribute__((ext_vector_type(4)));

// ---- DPP wave-total: sum across 64 lanes, broadcast via lane 63 ----
template <int CTRL>
__device__ __forceinline__ float dpp_add(float x) {
    int y = __builtin_amdgcn_update_dpp(0, __builtin_bit_cast(int, x),
                                        CTRL, 0xF, 0xF, true);
    return x + __builtin_bit_cast(float, y);
}

__device__ __forceinline__ float wave_total(float x) {
    x = dpp_add<0x111>(x);   // row_shr:1
    x = dpp_add<0x112>(x);   // row_shr:2
    x = dpp_add<0x114>(x);   // row_shr:4
    x = dpp_add<0x118>(x);   // row_shr:8
    x = dpp_add<0x142>(x);   // row_bcast:15
    x = dpp_add<0x143>(x);   // row_bcast:31 -> lane 63 has full sum
    return __builtin_bit_cast(float,
        __builtin_amdgcn_readlane(__builtin_bit_cast(int, x), 63));
}

__device__ __forceinline__ float bcastf(float v, int l) {
    return __builtin_bit_cast(float,
        __builtin_amdgcn_readlane(__builtin_bit_cast(int, v), l));
}

__device__ __forceinline__ float hsum4(v4f a) {
    return (a.x + a.y) + (a.z + a.w);
}

// f32 data read as bf16 at even 16-bit halves -> huge/NaN values. Wave-level
// (__any over 64 lanes); lane-indexed so all waves get identical results.
__device__ __forceinline__ bool detect_bf16(const void* embed, int lane) {
    const unsigned short* u = (const unsigned short*)embed;
    int bad = 0;
    for (int i = 2 * lane; i < 4096; i += 128) {
        float v = __uint_as_float(((unsigned int)u[i]) << 16);
        if (!(fabsf(v) < 1e4f)) bad = 1;
    }
    return !__any(bad);
}

template <bool BF>
__device__ __forceinline__ float ldf(const void* p, int i) {
    if (BF) return __bfloat162float(((const __hip_bfloat16*)p)[i]);
    return ((const float*)p)[i];
}

// Register-resident encoder (R14-verified): wave `wid` encodes tokens
// 16wid..16wid+16 simultaneously; all broadcasts via v_readlane on the
// wave's own SIMD; weights stream from global with next-iter prefetch.
template <bool BF>
__device__ void encode_reg(int wid, int lane, int tl, const void* embed,
                           const void* w1, const void* b1, const void* w2,
                           const void* b2, const void* ln_g, const void* ln_b,
                           const void* wk, const void* wvp, const void* wq,
                           float* __restrict__ k_lds, float* __restrict__ v_lds,
                           float* __restrict__ thr2_lds,
                           float* __restrict__ qrow_s) {
    const int tbase = wid * 16;
    float h[16];
    #pragma unroll
    for (int it = 0; it < 16; ++it)
        h[it] = ldf<BF>(embed, (tbase + it) * HD + lane);

    // ---- FFN1: u[it][e] = relu(sum_j h[it][j]*w1[j][e]+b1[e]); e=lane,lane+64
    float u0[16], u1[16];
    #pragma unroll
    for (int it = 0; it < 16; ++it) { u0[it] = 0.f; u1[it] = 0.f; }
    float a0 = ldf<BF>(w1, 0 * TWOH + lane), b0 = ldf<BF>(w1, 0 * TWOH + lane + HD);
    float a1 = ldf<BF>(w1, 1 * TWOH + lane), b1w = ldf<BF>(w1, 1 * TWOH + lane + HD);
    float a2 = ldf<BF>(w1, 2 * TWOH + lane), b2w = ldf<BF>(w1, 2 * TWOH + lane + HD);
    float a3 = ldf<BF>(w1, 3 * TWOH + lane), b3w = ldf<BF>(w1, 3 * TWOH + lane + HD);
    #pragma unroll 1
    for (int j4 = 0; j4 < 16; ++j4) {
        float na0 = 0, nb0 = 0, na1 = 0, nb1 = 0,
              na2 = 0, nb2 = 0, na3 = 0, nb3 = 0;
        if (j4 < 15) {                       // prefetch next 4 rows
            const int j = (j4 + 1) * 4;
            na0 = ldf<BF>(w1, (j + 0) * TWOH + lane);
            nb0 = ldf<BF>(w1, (j + 0) * TWOH + lane + HD);
            na1 = ldf<BF>(w1, (j + 1) * TWOH + lane);
            nb1 = ldf<BF>(w1, (j + 1) * TWOH + lane + HD);
            na2 = ldf<BF>(w1, (j + 2) * TWOH + lane);
            nb2 = ldf<BF>(w1, (j + 2) * TWOH + lane + HD);
            na3 = ldf<BF>(w1, (j + 3) * TWOH + lane);
            nb3 = ldf<BF>(w1, (j + 3) * TWOH + lane + HD);
        }
        const int j = j4 * 4;
        #pragma unroll
        for (int it = 0; it < 16; ++it) {
            const float s0 = bcastf(h[it], j + 0);   // own-SIMD broadcast
            const float s1 = bcastf(h[it], j + 1);
            const float s2 = bcastf(h[it], j + 2);
            const float s3 = bcastf(h[it], j + 3);
            u0[it] = fmaf(s0, a0, u0[it]); u1[it] = fmaf(s0, b0, u1[it]);
            u0[it] = fmaf(s1, a1, u0[it]); u1[it] = fmaf(s1, b1w, u1[it]);
            u0[it] = fmaf(s2, a2, u0[it]); u1[it] = fmaf(s2, b2w, u1[it]);
            u0[it] = fmaf(s3, a3, u0[it]); u1[it] = fmaf(s3, b3w, u1[it]);
        }
        a0 = na0; b0 = nb0; a1 = na1; b1w = nb1;
        a2 = na2; b2w = nb2; a3 = na3; b3w = nb3;
    }
    const float bb0 = ldf<BF>(b1, lane), bb1 = ldf<BF>(b1, lane + HD);
    #pragma unroll
    for (int it = 0; it < 16; ++it) {
        u0[it] = fmaxf(u0[it] + bb0, 0.f);
        u1[it] = fmaxf(u1[it] + bb1, 0.f);
    }

    // ---- FFN2: f[it] = sum_e u[it][e]*w2[e][lane]  (pass A: u0, pass B: u1)
    float f[16];
    #pragma unroll
    for (int it = 0; it < 16; ++it) f[it] = 0.f;
    {   // pass A: e = 0..63 from u0
        float w0 = ldf<BF>(w2, 0 * HD + lane), w1v = ldf<BF>(w2, 1 * HD + lane);
        float w2v = ldf<BF>(w2, 2 * HD + lane), w3 = ldf<BF>(w2, 3 * HD + lane);
        #pragma unroll 1
        for (int e4 = 0; e4 < 16; ++e4) {
            float n0 = 0, n1 = 0, n2 = 0, n3 = 0;
            if (e4 < 15) {
                const int e = (e4 + 1) * 4;
                n0 = ldf<BF>(w2, (e + 0) * HD + lane);
                n1 = ldf<BF>(w2, (e + 1) * HD + lane);
                n2 = ldf<BF>(w2, (e + 2) * HD + lane);
                n3 = ldf<BF>(w2, (e + 3) * HD + lane);
            }
            const int e = e4 * 4;
            #pragma unroll
            for (int it = 0; it < 16; ++it) {
                f[it] = fmaf(bcastf(u0[it], e + 0), w0, f[it]);
                f[it] = fmaf(bcastf(u0[it], e + 1), w1v, f[it]);
                f[it] = fmaf(bcastf(u0[it], e + 2), w2v, f[it]);
                f[it] = fmaf(bcastf(u0[it], e + 3), w3, f[it]);
            }
            w0 = n0; w1v = n1; w2v = n2; w3 = n3;
        }
    }
    {   // pass B: e = 64..127 from u1
        float w0 = ldf<BF>(w2, 64 * HD + lane), w1v = ldf<BF>(w2, 65 * HD + lane);
        float w2v = ldf<BF>(w2, 66 * HD + lane), w3 = ldf<BF>(w2, 67 * HD + lane);
        #pragma unroll 1
        for (int e4 = 0; e4 < 16; ++e4) {
            float n0 = 0, n1 = 0, n2 = 0, n3 = 0;
            if (e4 < 15) {
                const int e = HD + (e4 + 1) * 4;
                n0 = ldf<BF>(w2, (e + 0) * HD + lane);
                n1 = ldf<BF>(w2, (e + 1) * HD + lane);
                n2 = ldf<BF>(w2, (e + 2) * HD + lane);
                n3 = ldf<BF>(w2, (e + 3) * HD + lane);
            }
            const int e = e4 * 4;
            #pragma unroll
            for (int it = 0; it < 16; ++it) {
                f[it] = fmaf(bcastf(u1[it], e + 0), w0, f[it]);
                f[it] = fmaf(bcastf(u1[it], e + 1), w1v, f[it]);
                f[it] = fmaf(bcastf(u1[it], e + 2), w2v, f[it]);
                f[it] = fmaf(bcastf(u1[it], e + 3), w3, f[it]);
            }
            w0 = n0; w1v = n1; w2v = n2; w3 = n3;
        }
    }

    // ---- LayerNorm per token (eps 1e-5) ----
    const float b2v = ldf<BF>(b2, lane);
    const float lg = ldf<BF>(ln_g, lane), lb = ldf<BF>(ln_b, lane);
    float hn[16];
    #pragma unroll 1
    for (int it = 0; it < 16; ++it) {
        float y = h[it] + f[it] + b2v;
        float mu  = wave_total(y) * 0.015625f;
        float dvv = y - mu;
        float var = wave_total(dvv * dvv) * 0.015625f;
        hn[it] = fmaf(dvv * (1.f / sqrtf(var + 1e-5f)), lg, lb);
    }

    // ---- k/v projections ----
    float k[16], v[16];
    #pragma unroll
    for (int it = 0; it < 16; ++it) { k[it] = 0.f; v[it] = 0.f; }
    float ka = ldf<BF>(wk, 0 * HD + lane), kb = ldf<BF>(wk, 1 * HD + lane);
    float kc = ldf<BF>(wk, 2 * HD + lane), kd = ldf<BF>(wk, 3 * HD + lane);
    float va = ldf<BF>(wvp, 0 * HD + lane), vb = ldf<BF>(wvp, 1 * HD + lane);
    float vc = ldf<BF>(wvp, 2 * HD + lane), vd = ldf<BF>(wvp, 3 * HD + lane);
    #pragma unroll 1
    for (int j4 = 0; j4 < 16; ++j4) {
        float nka = 0, nkb = 0, nkc = 0, nkd = 0,
              nva = 0, nvb = 0, nvc = 0, nvd = 0;
        if (j4 < 15) {
            const int j = (j4 + 1) * 4;
            nka = ldf<BF>(wk, (j + 0) * HD + lane);
            nkb = ldf<BF>(wk, (j + 1) * HD + lane);
            nkc = ldf<BF>(wk, (j + 2) * HD + lane);
            nkd = ldf<BF>(wk, (j + 3) * HD + lane);
            nva = ldf<BF>(wvp, (j + 0) * HD + lane);
            nvb = ldf<BF>(wvp, (j + 1) * HD + lane);
            nvc = ldf<BF>(wvp, (j + 2) * HD + lane);
            nvd = ldf<BF>(wvp, (j + 3) * HD + lane);
        }
        const int j = j4 * 4;
        #pragma unroll
        for (int it = 0; it < 16; ++it) {
            const float s0 = bcastf(hn[it], j + 0);
            const float s1 = bcastf(hn[it], j + 1);
            const float s2 = bcastf(hn[it], j + 2);
            const float s3 = bcastf(hn[it], j + 3);
            k[it] = fmaf(s0, ka, k[it]); v[it] = fmaf(s0, va, v[it]);
            k[it] = fmaf(s1, kb, k[it]); v[it] = fmaf(s1, vb, v[it]);
            k[it] = fmaf(s2, kc, k[it]); v[it] = fmaf(s2, vc, v[it]);
            k[it] = fmaf(s3, kd, k[it]); v[it] = fmaf(s3, vd, v[it]);
        }
        ka = nka; kb = nkb; kc = nkc; kd = nkd;
        va = nva; vb = nvb; vc = nvc; vd = nvd;
    }

    // normalize + write tables (stride KS=68)
    #pragma unroll 1
    for (int it = 0; it < 16; ++it) {
        const int t = tbase + it;
        float nk = sqrtf(wave_total(k[it] * k[it]));
        float kn = k[it] / fmaxf(nk, 1e-12f);       // k / max(||k||, NORM_EPS)
        float nv2 = wave_total(v[it] * v[it]);
        k_lds[t * KS + lane] = kn;
        v_lds[t * KS + lane] = v[it];
        if (lane == 0) thr2_lds[t] = 0.16f * nv2;   // (0.4*||v||)^2
    }

    // q only for token tl (wave-uniform branch)
    if (tl >= tbase && tl < tbase + 16) {
        const int it = tl - tbase;
        float q = 0.f;
        #pragma unroll
        for (int j4 = 0; j4 < 16; ++j4) {
            const int j = j4 * 4;
            q = fmaf(bcastf(hn[it], j + 0), ldf<BF>(wq, (j + 0) * HD + lane), q);
            q = fmaf(bcastf(hn[it], j + 1), ldf<BF>(wq, (j + 1) * HD + lane), q);
            q = fmaf(bcastf(hn[it], j + 2), ldf<BF>(wq, (j + 2) * HD + lane), q);
            q = fmaf(bcastf(hn[it], j + 3), ldf<BF>(wq, (j + 3) * HD + lane), q);
        }
        qrow_s[lane] = q;
    }
}

// Single plain launch: 256 blocks x 4 waves (one per SIMD).
// Phase 1: register-resident encoder. Phase 2: fire loop with SPECULATIVE
// next-fire execution: after firing t, token t is exactly clean (G[t][t]=1
// => dv_t -> 0), so fireset_spec = fireset & ~(1<<t) predicts the next
// pending step pre-barrier. After __syncthreads we issue the 4 pbuf
// exchange reads, then run the speculative update while they're in flight
// (g2 issued first -> lgkmcnt(4) wait covers only g2). After the real
// ballot: commit (skip next update, -90 cyc) or restore dv/R (+65 cyc).
// Identical fma order on both paths -> bitwise-identical results.
__global__ __launch_bounds__(256, 1) void fused_kernel(
    const int* __restrict__ x, const void* embed, const void* w1,
    const void* b1, const void* w2, const void* b2, const void* ln_g,
    const void* ln_b, const void* wk, const void* wvp, const void* wq,
    const void* wo, const void* bo, void* __restrict__ out) {
    const int b = blockIdx.x, tid = threadIdx.x;
    const int wid = tid >> 6, lane = tid & 63;
    __shared__ __align__(16) float k_lds[64 * KS];
    __shared__ __align__(16) float v_lds[64 * KS];
    __shared__ __align__(16) float g_lds[4096];
    __shared__ int   tok_lds[SEQ];
    __shared__ float thr2_lds[64];
    __shared__ float qrow_s[64];
    __shared__ float pbuf[2][4][64];     // ping-pong nd2 partials
    __shared__ __align__(16) float rd_lds[64];

    // stage token stream (coalesced over 256 threads)
    const int* xr = x + b * SEQ;
    #pragma unroll
    for (int c = 0; c < 8; ++c) tok_lds[c * 256 + tid] = xr[c * 256 + tid];
    const int tl = xr[SEQ - 1];

    // Phase 1: encoder
    const bool bf = detect_bf16(embed, lane);
    if (bf)
        encode_reg<true>(wid, lane, tl, embed, w1, b1, w2, b2, ln_g, ln_b,
                         wk, wvp, wq, k_lds, v_lds, thr2_lds, qrow_s);
    else
        encode_reg<false>(wid, lane, tl, embed, w1, b1, w2, b2, ln_g, ln_b,
                          wk, wvp, wq, k_lds, v_lds, thr2_lds, qrow_s);
    __syncthreads();                     // k/v/thr2/qrow visible

    const float thr2 = thr2_lds[lane];

    // k_lane full row into registers (stride-68 -> 8-way max conflicts)
    v4f kreg[16];
    #pragma unroll
    for (int i = 0; i < 16; ++i)
        kreg[i] = *(const v4f*)&k_lds[lane * KS + i * 4];

    // cq_lane = k_lane . q_tl  (qrow_s uniform reads -> broadcast)
    v4f cacc = {0.f, 0.f, 0.f, 0.f};
    #pragma unroll
    for (int i = 0; i < 16; ++i) {
        const v4f qv = *(const v4f*)&qrow_s[i * 4];
        cacc = __builtin_elementwise_fma(qv, kreg[i], cacc);
    }
    const float cq = hsum4(cacc);

    // G build: wave w computes rows [16w,16w+16): G[t][lane] = k_t . k_lane
    #pragma unroll 1
    for (int t0 = 0; t0 < 16; ++t0) {
        const int t = wid * 16 + t0;
        const float* kt = &k_lds[t * KS];    // uniform -> LDS broadcast
        v4f a = {0.f, 0.f, 0.f, 0.f};
        #pragma unroll
        for (int i = 0; i < 16; ++i) {
            const v4f kv = *(const v4f*)&kt[i * 4];
            a = __builtin_elementwise_fma(kv, kreg[i], a);
        }
        g_lds[t * HD + lane] = hsum4(a);
    }

    // dv quarter = v_lane[16wid..16wid+16); R = 0; partial nd2
    v4f dv[4], R[4], dv_sv[4], R_sv[4];
    v4f acc = {0.f, 0.f, 0.f, 0.f};
    #pragma unroll
    for (int i = 0; i < 4; ++i) {
        dv[i] = *(const v4f*)&v_lds[lane * KS + wid * 16 + i * 4];
        R[i]  = (v4f){0.f, 0.f, 0.f, 0.f};
        acc   = __builtin_elementwise_fma(dv[i], dv[i], acc);
    }
    pbuf[0][wid][lane] = hsum4(acc);
    int pp = 1;
    __syncthreads();                       // g_lds + pbuf[0] visible
    float nd2 = ((pbuf[0][0][lane] + pbuf[0][1][lane]) +
                 (pbuf[0][2][lane] + pbuf[0][3][lane]));
    unsigned long long fireset = __ballot(nd2 > thr2);

    // Phase 2: fire loop with speculation
    int chunk = tok_lds[lane];
    #pragma unroll 1
    for (int c = 0; c < NCH; ++c) {
        int nxt = 0;
        if (c + 1 < NCH) nxt = tok_lds[(c + 1) * 64 + lane];
        unsigned long long pend = __ballot((int)((fireset >> chunk) & 1ull));
        bool applied = false;        // dv/R already hold update for ctz(pend)
        float q4h_sp = 0.f;          // its nd2 partial (valid when applied)
        while (pend) {
            const int s = __builtin_ctzll(pend);
            const int t = __builtin_amdgcn_readlane(chunk, s);
            float q4h;
            if (applied) {
                q4h = q4h_sp;                      // update pre-applied
            } else {
                const float g   = g_lds[t * HD + lane];
                const float cqt = bcastf(cq, t);
                const v4f gs  = {-g, -g, -g, -g};
                const v4f cqs = {cqt, cqt, cqt, cqt};
                v4f q4 = {0.f, 0.f, 0.f, 0.f};
                #pragma unroll
                for (int i = 0; i < 4; ++i) {
                    v4f sve;                       // delta_t quarter (own regs)
                    sve.x = bcastf(dv[i].x, t);
                    sve.y = bcastf(dv[i].y, t);
                    sve.z = bcastf(dv[i].z, t);
                    sve.w = bcastf(dv[i].w, t);
                    dv[i] = __builtin_elementwise_fma(gs, sve, dv[i]);
                    R[i]  = __builtin_elementwise_fma(cqs, sve, R[i]);
                    q4    = __builtin_elementwise_fma(dv[i], dv[i], q4);
                }
                q4h = hsum4(q4);
            }
            pbuf[pp][wid][lane] = q4h;

            // pre-barrier: speculation target (token t is now exactly clean)
            const unsigned long long above =
                (s >= 63) ? 0ull : (~0ull << (s + 1));
            const unsigned long long fs_sp = fireset & ~(1ull << t);
            unsigned long long pend_sp =
                __ballot((int)((fs_sp >> chunk) & 1ull)) & above;

            __syncthreads();                       // single barrier per fire
            const float p0 = pbuf[pp][0][lane];    // exchange reads in flight
            const float p1 = pbuf[pp][1][lane];
            const float p2 = pbuf[pp][2][lane];
            const float p3 = pbuf[pp][3][lane];
            int  s_sp  = 0;
            bool did_sp = false;
            if (pend_sp) {                         // speculative update
                s_sp = __builtin_ctzll(pend_sp);
                const int t2 = __builtin_amdgcn_readlane(chunk, s_sp);
                const float g2   = g_lds[t2 * HD + lane];
                const float cqt2 = bcastf(cq, t2);
                #pragma unroll
                for (int i = 0; i < 4; ++i) { dv_sv[i] = dv[i]; R_sv[i] = R[i]; }
                const v4f gs2  = {-g2, -g2, -g2, -g2};
                const v4f cqs2 = {cqt2, cqt2, cqt2, cqt2};
                v4f q4b = {0.f, 0.f, 0.f, 0.f};
                #pragma unroll
                for (int i = 0; i < 4; ++i) {
                    v4f sve;
                    sve.x = bcastf(dv[i].x, t2);
                    sve.y = bcastf(dv[i].y, t2);
                    sve.z = bcastf(dv[i].z, t2);
                    sve.w = bcastf(dv[i].w, t2);
                    dv[i] = __builtin_elementwise_fma(gs2, sve, dv[i]);
                    R[i]  = __builtin_elementwise_fma(cqs2, sve, R[i]);
                    q4b   = __builtin_elementwise_fma(dv[i], dv[i], q4b);
                }
                q4h_sp = hsum4(q4b);
                did_sp = true;
            }
            const float nd2n = (p0 + p1) + (p2 + p3);
            pp ^= 1;                               // ping-pong: no 2nd barrier
            fireset = __ballot(nd2n > thr2);
            pend = __ballot((int)((fireset >> chunk) & 1ull)) & above;
            if (did_sp && pend != 0ull && __builtin_ctzll(pend) == s_sp) {
                applied = true;                    // hit: next update pre-done
            } else {
                if (did_sp) {                      // miss: rollback
                    #pragma unroll
                    for (int i = 0; i < 4; ++i) { dv[i] = dv_sv[i]; R[i] = R_sv[i]; }
                }
                applied = false;
            }
        }
        chunk = nxt;
    }

    // read = relu(R): wave w holds components [16wid..16wid+16) in each lane
    if (lane == 0) {
        #pragma unroll
        for (int i = 0; i < 4; ++i) {
            v4f r = R[i];
            r.x = fmaxf(r.x, 0.f); r.y = fmaxf(r.y, 0.f);
            r.z = fmaxf(r.z, 0.f); r.w = fmaxf(r.w, 0.f);
            *(v4f*)&rd_lds[wid * 16 + i * 4] = r;
        }
    }
    __syncthreads();

    // out[b][c] = sum_j rd[j] * wo[j][c] + bo[c]  — wave 0 only (lane = c)
    if (wid == 0) {
        if (bf) {
            float acc2 = __bfloat162float(((const __hip_bfloat16*)bo)[lane]);
            #pragma unroll 8
            for (int j = 0; j < HD; ++j)
                acc2 = fmaf(rd_lds[j],
                    __bfloat162float(((const __hip_bfloat16*)wo)[j * HD + lane]),
                    acc2);
            ((__hip_bfloat16*)out)[b * HD + lane] = __float2bfloat16(acc2);
        } else {
            float acc2 = ((const float*)bo)[lane];
            #pragma unroll 8
            for (int j = 0; j < HD; ++j)
                acc2 = fmaf(rd_lds[j], ((const float*)wo)[j * HD + lane], acc2);
            ((float*)out)[b * HD + lane] = acc2;
        }
    }
}

extern "C" void kernel_launch(void* const* d_in, const int* in_sizes, int n_in,
                              void* d_out, int out_size, void* d_ws, size_t ws_size,
                              hipStream_t stream) {
    const int* x      = (const int*)d_in[0];
    const void* embed = d_in[1];
    const void* w1    = d_in[2];
    const void* b1    = d_in[3];
    const void* w2    = d_in[4];
    const void* b2    = d_in[5];
    const void* ln_g  = d_in[6];
    const void* ln_b  = d_in[7];
    const void* wk    = d_in[8];
    const void* wvp   = d_in[9];
    const void* wq    = d_in[10];
    const void* wo    = d_in[11];
    const void* bo    = d_in[12];

    fused_kernel<<<NB, 256, 0, stream>>>(x, embed, w1, b1, w2, b2, ln_g, ln_b,
                                         wk, wvp, wq, wo, bo, d_out);
}